// Round 1
// baseline (555.984 us; speedup 1.0000x reference)
//
#include <hip/hip_runtime.h>
#include <math.h>

#define NN 50000
#define NE 800000

// workspace layout (offsets in floats/words)
#define OFF_DEG    0          // float[NN]
#define OFF_CNT    50000      // int[NN]
#define OFF_ROWPTR 100000     // int[NN+1]
#define OFF_FILL   150008     // int[NN]
#define OFF_ELIST  200008     // float2[NE]
#define OFF_T1X    1800008    // float[NN*64]
#define OFF_T1H    5000008
#define OFF_P2X    8200008
#define OFF_P2H    11400008

__global__ void k_zero(int* __restrict__ p, int n) {
  int i = blockIdx.x * blockDim.x + threadIdx.x;
  if (i < n) p[i] = 0;
}

__global__ void k_hist(const int* __restrict__ src, const int* __restrict__ dst,
                       const float* __restrict__ w, float* __restrict__ deg,
                       int* __restrict__ cnt) {
  int e = blockIdx.x * 256 + threadIdx.x;
  if (e >= NE) return;
  atomicAdd(&deg[src[e]], w[e]);
  atomicAdd(&cnt[dst[e]], 1);
}

// single-block inclusive scan over cnt -> rowptr (exclusive start in fill)
__global__ void k_scan(const int* __restrict__ cnt, int* __restrict__ rowptr,
                       int* __restrict__ fill) {
  __shared__ int wsum[16];
  __shared__ int carry_s;
  int t = threadIdx.x, lane = t & 63, w = t >> 6;
  if (t == 0) carry_s = 0;
  __syncthreads();
  for (int base = 0; base < NN; base += 1024) {
    int i = base + t;
    int v = (i < NN) ? cnt[i] : 0;
    int val = v;
#pragma unroll
    for (int off = 1; off < 64; off <<= 1) {
      int u = __shfl_up(val, off, 64);
      if (lane >= off) val += u;
    }
    if (lane == 63) wsum[w] = val;
    __syncthreads();
    if (w == 0) {
      int s = (lane < 16) ? wsum[lane] : 0;
#pragma unroll
      for (int off = 1; off < 16; off <<= 1) {
        int u = __shfl_up(s, off, 64);
        if (lane >= off) s += u;
      }
      if (lane < 16) wsum[lane] = s;  // inclusive wave sums
    }
    __syncthreads();
    int wbase = (w > 0) ? wsum[w - 1] : 0;
    int carry = carry_s;
    int incl = carry + wbase + val;
    if (i < NN) {
      rowptr[i + 1] = incl;
      fill[i] = incl - v;  // exclusive prefix = start slot
    }
    __syncthreads();
    if (t == 1023) carry_s = carry + wsum[15];
    __syncthreads();
  }
  if (t == 0) rowptr[0] = 0;
}

__global__ void k_scatter(const int* __restrict__ src, const int* __restrict__ dst,
                          const float* __restrict__ wgt, const float* __restrict__ deg,
                          int* __restrict__ fill, float2* __restrict__ elist) {
  int e = blockIdx.x * 256 + threadIdx.x;
  if (e >= NE) return;
  int s = src[e], d = dst[e];
  float ds = deg[s], dd = deg[d];
  float a = (ds > 0.f) ? rsqrtf(ds) : 0.f;
  float b = (dd > 0.f) ? rsqrtf(dd) : 0.f;
  float nm = -a * wgt[e] * b;
  int pos = atomicAdd(&fill[d], 1);
  elist[pos] = make_float2(__int_as_float(s), nm);
}

// gather-based propagation: out[n] = sum_{e: dst=n} norm_e * in[src_e]
// one wave per node, lane = channel; does X and H tensors together
__global__ void k_prop(const int* __restrict__ rowptr, const float2* __restrict__ elist,
                       const float* __restrict__ inX, const float* __restrict__ inH,
                       float* __restrict__ outX, float* __restrict__ outH) {
  int n = blockIdx.x * 4 + (threadIdx.x >> 6);
  int c = threadIdx.x & 63;
  if (n >= NN) return;
  int beg = rowptr[n], end = rowptr[n + 1];
  float ax = 0.f, ah = 0.f;
  for (int i = beg; i < end; ++i) {
    float2 en = elist[i];
    int s = __float_as_int(en.x);
    float nm = en.y;
    ax += nm * inX[s * 64 + c];
    ah += nm * inH[s * 64 + c];
  }
  outX[n * 64 + c] = ax;
  outH[n * 64 + c] = ah;
}

// fused: build [X,T1X,2*P2X-X,H,T1H,2*P2H-H] (N x 384), multiply by combined
// (384 x 256) weights, add biases, LSTM gate math, write H_new and C_new.
__global__ __launch_bounds__(256, 3) void k_gates(
    const float* __restrict__ X, const float* __restrict__ H, const float* __restrict__ C,
    const float* __restrict__ T1X, const float* __restrict__ P2X,
    const float* __restrict__ T1H, const float* __restrict__ P2H,
    const float* __restrict__ Wx, const float* __restrict__ Wh,
    const float* __restrict__ bx, const float* __restrict__ bh,
    const float* __restrict__ wc, const float* __restrict__ bg,
    float* __restrict__ out) {
  __shared__ float smem[32 * 384];  // 48 KB; reused as pre[32][256] later
  const int t = threadIdx.x;
  const int base = blockIdx.x * 32;

  // stage inputs: lin[m][k], k = seg*64 + c
  for (int i = t; i < 32 * 384; i += 256) {
    int m = i / 384;
    int k = i - m * 384;
    int n = base + m;
    float v = 0.f;
    if (n < NN) {
      int seg = k >> 6;
      int c = k & 63;
      int idx = n * 64 + c;
      switch (seg) {
        case 0: v = X[idx]; break;
        case 1: v = T1X[idx]; break;
        case 2: v = 2.f * P2X[idx] - X[idx]; break;
        case 3: v = H[idx]; break;
        case 4: v = T1H[idx]; break;
        default: v = 2.f * P2H[idx] - H[idx]; break;
      }
    }
    smem[m * 384 + k] = v;
  }
  __syncthreads();

  const int wave = t >> 6;
  const int lane = t & 63;
  const int g = lane >> 4;           // gate of this lane's 4 output cols
  const int cout4 = (lane & 15) * 4; // first of 4 consecutive out channels

  float acc[8][4];
#pragma unroll
  for (int mi = 0; mi < 8; ++mi)
#pragma unroll
    for (int jj = 0; jj < 4; ++jj) acc[mi][jj] = 0.f;

#pragma unroll
  for (int seg = 0; seg < 6; ++seg) {
    const float* Wsel = (seg < 3) ? Wx : Wh;
    const int scheb = (seg < 3) ? seg : seg - 3;
    const float* Wbase = Wsel + ((g * 3 + scheb) * 64) * 64 + cout4;
    const float* lbase = &smem[(wave * 8) * 384 + seg * 64];
    for (int kc = 0; kc < 64; kc += 4) {
      float4 w0 = *(const float4*)&Wbase[(kc + 0) * 64];
      float4 w1 = *(const float4*)&Wbase[(kc + 1) * 64];
      float4 w2 = *(const float4*)&Wbase[(kc + 2) * 64];
      float4 w3 = *(const float4*)&Wbase[(kc + 3) * 64];
#pragma unroll
      for (int mi = 0; mi < 8; ++mi) {
        float4 lv = *(const float4*)&lbase[mi * 384 + kc];
        acc[mi][0] += lv.x * w0.x + lv.y * w1.x + lv.z * w2.x + lv.w * w3.x;
        acc[mi][1] += lv.x * w0.y + lv.y * w1.y + lv.z * w2.y + lv.w * w3.y;
        acc[mi][2] += lv.x * w0.z + lv.y * w1.z + lv.z * w2.z + lv.w * w3.z;
        acc[mi][3] += lv.x * w0.w + lv.y * w1.w + lv.z * w2.w + lv.w * w3.w;
      }
    }
  }
  __syncthreads();

  // dump pre-activations into smem (overlay): pre[m][j]
#pragma unroll
  for (int mi = 0; mi < 8; ++mi) {
    int m = wave * 8 + mi;
    float4 v4 = make_float4(acc[mi][0], acc[mi][1], acc[mi][2], acc[mi][3]);
    *(float4*)&smem[m * 256 + g * 64 + cout4] = v4;
  }
  __syncthreads();

  // gate math + store
  for (int i = t; i < 32 * 64; i += 256) {
    int m = i >> 6;
    int cc = i & 63;
    int n = base + m;
    if (n >= NN) continue;
    const float* pre = &smem[m * 256];
    float cv = C[n * 64 + cc];
    float bI = bx[cc] + bh[cc] + bg[cc];
    float bF = bx[64 + cc] + bh[64 + cc] + bg[64 + cc];
    float bT = bx[128 + cc] + bh[128 + cc] + bg[128 + cc];
    float bO = bx[192 + cc] + bh[192 + cc] + bg[192 + cc];
    float aI = pre[cc] + wc[cc] * cv + bI;
    float aF = pre[64 + cc] + wc[64 + cc] * cv + bF;
    float aT = pre[128 + cc] + bT;
    float I = 1.f / (1.f + expf(-aI));
    float F = 1.f / (1.f + expf(-aF));
    float T = tanhf(aT);
    float Cn = F * cv + I * T;
    float aO = pre[192 + cc] + wc[128 + cc] * Cn + bO;
    float O = 1.f / (1.f + expf(-aO));
    out[n * 64 + cc] = O * tanhf(Cn);
    out[NN * 64 + n * 64 + cc] = Cn;
  }
}

extern "C" void kernel_launch(void* const* d_in, const int* in_sizes, int n_in,
                              void* d_out, int out_size, void* d_ws, size_t ws_size,
                              hipStream_t stream) {
  const float* X  = (const float*)d_in[0];
  const int*   ei = (const int*)d_in[1];
  const float* ew = (const float*)d_in[2];
  const float* H  = (const float*)d_in[3];
  const float* C  = (const float*)d_in[4];
  const float* Wx = (const float*)d_in[5];
  const float* bx = (const float*)d_in[6];
  const float* Wh = (const float*)d_in[7];
  const float* bh = (const float*)d_in[8];
  const float* wc = (const float*)d_in[9];
  const float* bg = (const float*)d_in[10];
  float* out = (float*)d_out;
  float* ws = (float*)d_ws;

  const int* src = ei;
  const int* dst = ei + NE;
  float* deg = ws + OFF_DEG;
  int* cnt = (int*)(ws + OFF_CNT);
  int* rowptr = (int*)(ws + OFF_ROWPTR);
  int* fill = (int*)(ws + OFF_FILL);
  float2* elist = (float2*)(ws + OFF_ELIST);
  float* T1X = ws + OFF_T1X;
  float* T1H = ws + OFF_T1H;
  float* P2X = ws + OFF_P2X;
  float* P2H = ws + OFF_P2H;

  k_zero<<<(100000 + 255) / 256, 256, 0, stream>>>((int*)ws, 100000);
  k_hist<<<(NE + 255) / 256, 256, 0, stream>>>(src, dst, ew, deg, cnt);
  k_scan<<<1, 1024, 0, stream>>>(cnt, rowptr, fill);
  k_scatter<<<(NE + 255) / 256, 256, 0, stream>>>(src, dst, ew, deg, fill, elist);
  k_prop<<<(NN + 3) / 4, 256, 0, stream>>>(rowptr, elist, X, H, T1X, T1H);
  k_prop<<<(NN + 3) / 4, 256, 0, stream>>>(rowptr, elist, T1X, T1H, P2X, P2H);
  k_gates<<<(NN + 31) / 32, 256, 0, stream>>>(X, H, C, T1X, P2X, T1H, P2H,
                                              Wx, Wh, bx, bh, wc, bg, out);
}

// Round 2
// 434.439 us; speedup vs baseline: 1.2798x; 1.2798x over previous
//
#include <hip/hip_runtime.h>
#include <math.h>

#define NN 50000
#define NE 800000

typedef __attribute__((ext_vector_type(8))) short short8;
typedef __attribute__((ext_vector_type(4))) float f32x4;

// workspace layout (offsets in 4-byte words)
#define OFF_DEG    0          // float[NN]
#define OFF_CNT    50000      // int[NN]; reused as bf16 Wb[256*384] after k_scan
#define OFF_ROWPTR 100000     // int[NN+1]
#define OFF_FILL   150008     // int[NN]
#define OFF_ELIST  200008     // float2[NE]
#define OFF_T1X    1800008    // float[NN*64]
#define OFF_T1H    5000008
#define OFF_P2X    8200008
#define OFF_P2H    11400008

__device__ inline unsigned short f2bf(float f) {
  union { float f; unsigned u; } v; v.f = f;
  unsigned u = v.u;
  return (unsigned short)((u + 0x7FFFu + ((u >> 16) & 1u)) >> 16);
}

__global__ void k_zero(int* __restrict__ p, int n) {
  int i = blockIdx.x * blockDim.x + threadIdx.x;
  if (i < n) p[i] = 0;
}

__global__ void k_hist(const int* __restrict__ src, const int* __restrict__ dst,
                       const float* __restrict__ w, float* __restrict__ deg,
                       int* __restrict__ cnt) {
  int e = blockIdx.x * 256 + threadIdx.x;
  if (e >= NE) return;
  atomicAdd(&deg[src[e]], w[e]);
  atomicAdd(&cnt[dst[e]], 1);
}

// single-block scan over cnt -> rowptr, fill = exclusive prefix
__global__ void k_scan(const int* __restrict__ cnt, int* __restrict__ rowptr,
                       int* __restrict__ fill) {
  __shared__ int wsum[16];
  __shared__ int carry_s;
  int t = threadIdx.x, lane = t & 63, w = t >> 6;
  if (t == 0) carry_s = 0;
  __syncthreads();
  for (int base = 0; base < NN; base += 1024) {
    int i = base + t;
    int v = (i < NN) ? cnt[i] : 0;
    int val = v;
#pragma unroll
    for (int off = 1; off < 64; off <<= 1) {
      int u = __shfl_up(val, off, 64);
      if (lane >= off) val += u;
    }
    if (lane == 63) wsum[w] = val;
    __syncthreads();
    if (w == 0) {
      int s = (lane < 16) ? wsum[lane] : 0;
#pragma unroll
      for (int off = 1; off < 16; off <<= 1) {
        int u = __shfl_up(s, off, 64);
        if (lane >= off) s += u;
      }
      if (lane < 16) wsum[lane] = s;
    }
    __syncthreads();
    int wbase = (w > 0) ? wsum[w - 1] : 0;
    int carry = carry_s;
    int incl = carry + wbase + val;
    if (i < NN) {
      rowptr[i + 1] = incl;
      fill[i] = incl - v;
    }
    __syncthreads();
    if (t == 1023) carry_s = carry + wsum[15];
    __syncthreads();
  }
  if (t == 0) rowptr[0] = 0;
}

// combined weights -> bf16, layout Wb[col][kk] (col = gate*64+cout, kk = seg*64+k)
__global__ void k_wconv(const float* __restrict__ Wx, const float* __restrict__ Wh,
                        unsigned short* __restrict__ Wb) {
  int idx = blockIdx.x * 256 + threadIdx.x;
  if (idx >= 256 * 384) return;
  int col = idx / 384;
  int kk = idx - col * 384;
  int g = col >> 6, cc = col & 63;
  int seg = kk >> 6, k = kk & 63;
  float v = (seg < 3) ? Wx[((g * 3 + seg) * 64 + k) * 64 + cc]
                      : Wh[((g * 3 + (seg - 3)) * 64 + k) * 64 + cc];
  Wb[idx] = f2bf(v);
}

__global__ void k_scatter(const int* __restrict__ src, const int* __restrict__ dst,
                          const float* __restrict__ wgt, const float* __restrict__ deg,
                          int* __restrict__ fill, float2* __restrict__ elist) {
  int e = blockIdx.x * 256 + threadIdx.x;
  if (e >= NE) return;
  int s = src[e], d = dst[e];
  float ds = deg[s], dd = deg[d];
  float a = (ds > 0.f) ? rsqrtf(ds) : 0.f;
  float b = (dd > 0.f) ? rsqrtf(dd) : 0.f;
  float nm = -a * wgt[e] * b;
  int pos = atomicAdd(&fill[d], 1);
  elist[pos] = make_float2(__int_as_float(s), nm);
}

// gather propagation: 16 lanes per node, float4 per lane, X and H together
__global__ __launch_bounds__(256) void k_prop(
    const int* __restrict__ rowptr, const float2* __restrict__ elist,
    const float* __restrict__ inX, const float* __restrict__ inH,
    float* __restrict__ outX, float* __restrict__ outH) {
  int n = blockIdx.x * 16 + (threadIdx.x >> 4);
  int q = (threadIdx.x & 15) * 4;
  if (n >= NN) return;
  int beg = rowptr[n], end = rowptr[n + 1];
  float ax0 = 0.f, ax1 = 0.f, ax2 = 0.f, ax3 = 0.f;
  float ah0 = 0.f, ah1 = 0.f, ah2 = 0.f, ah3 = 0.f;
  int i = beg;
  for (; i + 1 < end; i += 2) {
    float2 e0 = elist[i];
    float2 e1 = elist[i + 1];
    int s0 = __float_as_int(e0.x);
    int s1 = __float_as_int(e1.x);
    float4 x0 = *(const float4*)&inX[s0 * 64 + q];
    float4 h0 = *(const float4*)&inH[s0 * 64 + q];
    float4 x1 = *(const float4*)&inX[s1 * 64 + q];
    float4 h1 = *(const float4*)&inH[s1 * 64 + q];
    ax0 += e0.y * x0.x; ax1 += e0.y * x0.y; ax2 += e0.y * x0.z; ax3 += e0.y * x0.w;
    ah0 += e0.y * h0.x; ah1 += e0.y * h0.y; ah2 += e0.y * h0.z; ah3 += e0.y * h0.w;
    ax0 += e1.y * x1.x; ax1 += e1.y * x1.y; ax2 += e1.y * x1.z; ax3 += e1.y * x1.w;
    ah0 += e1.y * h1.x; ah1 += e1.y * h1.y; ah2 += e1.y * h1.z; ah3 += e1.y * h1.w;
  }
  if (i < end) {
    float2 e0 = elist[i];
    int s0 = __float_as_int(e0.x);
    float4 x0 = *(const float4*)&inX[s0 * 64 + q];
    float4 h0 = *(const float4*)&inH[s0 * 64 + q];
    ax0 += e0.y * x0.x; ax1 += e0.y * x0.y; ax2 += e0.y * x0.z; ax3 += e0.y * x0.w;
    ah0 += e0.y * h0.x; ah1 += e0.y * h0.y; ah2 += e0.y * h0.z; ah3 += e0.y * h0.w;
  }
  *(float4*)&outX[n * 64 + q] = make_float4(ax0, ax1, ax2, ax3);
  *(float4*)&outH[n * 64 + q] = make_float4(ah0, ah1, ah2, ah3);
}

// MFMA gates: 64 nodes/block, A = [64][384] bf16 in LDS, B = Wb bf16 from L2.
// 4 waves; wave w computes all 64 rows x cols [w*64, w*64+64) = gate w.
__global__ __launch_bounds__(256, 2) void k_gates(
    const float* __restrict__ X, const float* __restrict__ H, const float* __restrict__ C,
    const float* __restrict__ T1X, const float* __restrict__ P2X,
    const float* __restrict__ T1H, const float* __restrict__ P2H,
    const unsigned short* __restrict__ Wb,
    const float* __restrict__ bx, const float* __restrict__ bh,
    const float* __restrict__ wc, const float* __restrict__ bg,
    float* __restrict__ out) {
  __shared__ float smem[16640];                 // 66560 B; A overlay then pre
  unsigned short* A = (unsigned short*)smem;    // [64][392] bf16 (pad 8)
  const int t = threadIdx.x;
  const int base = blockIdx.x * 64;

  // stage A: 64 rows x 384 k (6 segs of 64), fp32 -> bf16
  for (int g4 = t; g4 < 6144; g4 += 256) {      // 96 float4-groups per row
    int m = g4 / 96;
    int kk = (g4 - m * 96) * 4;
    int n = base + m;
    float4 v = make_float4(0.f, 0.f, 0.f, 0.f);
    if (n < NN) {
      int seg = kk >> 6;
      int c = kk & 63;
      int idx = n * 64 + c;
      switch (seg) {
        case 0: v = *(const float4*)&X[idx]; break;
        case 1: v = *(const float4*)&T1X[idx]; break;
        case 2: {
          float4 p = *(const float4*)&P2X[idx];
          float4 x = *(const float4*)&X[idx];
          v = make_float4(2.f * p.x - x.x, 2.f * p.y - x.y,
                          2.f * p.z - x.z, 2.f * p.w - x.w);
        } break;
        case 3: v = *(const float4*)&H[idx]; break;
        case 4: v = *(const float4*)&T1H[idx]; break;
        default: {
          float4 p = *(const float4*)&P2H[idx];
          float4 x = *(const float4*)&H[idx];
          v = make_float4(2.f * p.x - x.x, 2.f * p.y - x.y,
                          2.f * p.z - x.z, 2.f * p.w - x.w);
        } break;
      }
    }
    ushort4 b4 = make_ushort4(f2bf(v.x), f2bf(v.y), f2bf(v.z), f2bf(v.w));
    *(ushort4*)&A[m * 392 + kk] = b4;
  }
  __syncthreads();

  const int wv = t >> 6;         // wave id = gate
  const int l = t & 63;
  const int lr = l & 15;         // row (A) / col (B) within fragment
  const int lk = (l >> 4) * 8;   // k offset within chunk

  f32x4 acc[4][4];
#pragma unroll
  for (int rf = 0; rf < 4; ++rf)
#pragma unroll
    for (int cf = 0; cf < 4; ++cf) acc[rf][cf] = (f32x4){0.f, 0.f, 0.f, 0.f};

  const unsigned short* Ap = A + lr * 392 + lk;
  const unsigned short* Bp = Wb + (wv * 64 + lr) * 384 + lk;

#pragma unroll 2
  for (int kc = 0; kc < 12; ++kc) {
    short8 a[4], b[4];
#pragma unroll
    for (int rf = 0; rf < 4; ++rf)
      a[rf] = *(const short8*)(Ap + rf * (16 * 392) + kc * 32);
#pragma unroll
    for (int cf = 0; cf < 4; ++cf)
      b[cf] = *(const short8*)(Bp + cf * (16 * 384) + kc * 32);
#pragma unroll
    for (int rf = 0; rf < 4; ++rf)
#pragma unroll
      for (int cf = 0; cf < 4; ++cf)
        acc[rf][cf] = __builtin_amdgcn_mfma_f32_16x16x32_bf16(a[rf], b[cf], acc[rf][cf], 0, 0, 0);
  }
  __syncthreads();  // all waves done reading A before pre overlay

  // pre[64][260] fp32 overlay; row = rf*16 + (l>>4)*4 + q, col = wv*64 + cf*16 + lr
#pragma unroll
  for (int rf = 0; rf < 4; ++rf) {
#pragma unroll
    for (int cf = 0; cf < 4; ++cf) {
#pragma unroll
      for (int q = 0; q < 4; ++q) {
        int row = rf * 16 + (l >> 4) * 4 + q;
        int col = wv * 64 + cf * 16 + lr;
        smem[row * 260 + col] = acc[rf][cf][q];
      }
    }
  }
  __syncthreads();

  // gate math
  for (int i = t; i < 64 * 64; i += 256) {
    int m = i >> 6;
    int cc = i & 63;
    int n = base + m;
    if (n >= NN) continue;
    const float* pre = &smem[m * 260];
    float cv = C[n * 64 + cc];
    float bI = bx[cc] + bh[cc] + bg[cc];
    float bF = bx[64 + cc] + bh[64 + cc] + bg[64 + cc];
    float bT = bx[128 + cc] + bh[128 + cc] + bg[128 + cc];
    float bO = bx[192 + cc] + bh[192 + cc] + bg[192 + cc];
    float aI = pre[cc] + wc[cc] * cv + bI;
    float aF = pre[64 + cc] + wc[64 + cc] * cv + bF;
    float aT = pre[128 + cc] + bT;
    float I = 1.f / (1.f + expf(-aI));
    float F = 1.f / (1.f + expf(-aF));
    float T = tanhf(aT);
    float Cn = F * cv + I * T;
    float aO = pre[192 + cc] + wc[128 + cc] * Cn + bO;
    float O = 1.f / (1.f + expf(-aO));
    out[n * 64 + cc] = O * tanhf(Cn);
    out[NN * 64 + n * 64 + cc] = Cn;
  }
}

extern "C" void kernel_launch(void* const* d_in, const int* in_sizes, int n_in,
                              void* d_out, int out_size, void* d_ws, size_t ws_size,
                              hipStream_t stream) {
  const float* X  = (const float*)d_in[0];
  const int*   ei = (const int*)d_in[1];
  const float* ew = (const float*)d_in[2];
  const float* H  = (const float*)d_in[3];
  const float* C  = (const float*)d_in[4];
  const float* Wx = (const float*)d_in[5];
  const float* bx = (const float*)d_in[6];
  const float* Wh = (const float*)d_in[7];
  const float* bh = (const float*)d_in[8];
  const float* wc = (const float*)d_in[9];
  const float* bg = (const float*)d_in[10];
  float* out = (float*)d_out;
  float* ws = (float*)d_ws;

  const int* src = ei;
  const int* dst = ei + NE;
  float* deg = ws + OFF_DEG;
  int* cnt = (int*)(ws + OFF_CNT);
  unsigned short* Wb = (unsigned short*)(ws + OFF_CNT);  // reuse after scan
  int* rowptr = (int*)(ws + OFF_ROWPTR);
  int* fill = (int*)(ws + OFF_FILL);
  float2* elist = (float2*)(ws + OFF_ELIST);
  float* T1X = ws + OFF_T1X;
  float* T1H = ws + OFF_T1H;
  float* P2X = ws + OFF_P2X;
  float* P2H = ws + OFF_P2H;

  k_zero<<<(100000 + 255) / 256, 256, 0, stream>>>((int*)ws, 100000);
  k_hist<<<(NE + 255) / 256, 256, 0, stream>>>(src, dst, ew, deg, cnt);
  k_scan<<<1, 1024, 0, stream>>>(cnt, rowptr, fill);
  k_wconv<<<(256 * 384 + 255) / 256, 256, 0, stream>>>(Wx, Wh, Wb);
  k_scatter<<<(NE + 255) / 256, 256, 0, stream>>>(src, dst, ew, deg, fill, elist);
  k_prop<<<(NN + 15) / 16, 256, 0, stream>>>(rowptr, elist, X, H, T1X, T1H);
  k_prop<<<(NN + 15) / 16, 256, 0, stream>>>(rowptr, elist, T1X, T1H, P2X, P2H);
  k_gates<<<(NN + 63) / 64, 256, 0, stream>>>(X, H, C, T1X, P2X, T1H, P2H,
                                              Wb, bx, bh, wc, bg, out);
}

// Round 3
// 351.082 us; speedup vs baseline: 1.5836x; 1.2374x over previous
//
#include <hip/hip_runtime.h>
#include <math.h>

#define NN 50000
#define NE 800000

typedef __attribute__((ext_vector_type(8))) short short8;
typedef __attribute__((ext_vector_type(8))) unsigned short ushort8;
typedef __attribute__((ext_vector_type(4))) float f32x4;

// workspace layout (offsets in 4-byte words)
#define OFF_DEG    0          // float[NN]
#define OFF_CNT    50000      // int[NN]
#define OFF_ROWPTR 100000     // int[NN+1] (pad to 50008)
#define OFF_FILL   150008     // int[NN]
#define OFF_BSUM   200008     // int[64]
#define OFF_WB     200072     // ushort[256*384] = 49152 words
#define OFF_BIAS   249224     // float[256] combined bx+bh+bg
#define OFF_ELIST  249480     // float2[NE] = 1.6M words (8B aligned: even offset)
#define OFF_XB     1849480    // ushort[NN*64] = 1.6M words each
#define OFF_HB     3449480
#define OFF_T1X    5049480
#define OFF_T1H    6649480
#define OFF_T2X    8249480
#define OFF_T2H    9849480

__device__ inline unsigned short f2bf(float f) {
  union { float f; unsigned u; } v; v.f = f;
  unsigned u = v.u;
  return (unsigned short)((u + 0x7FFFu + ((u >> 16) & 1u)) >> 16);
}
__device__ inline float bf2f(unsigned short u) {
  return __uint_as_float(((unsigned)u) << 16);
}
__device__ inline float sigm(float x) { return 1.f / (1.f + __expf(-x)); }
__device__ inline float tanh_(float x) { return 1.f - 2.f / (__expf(2.f * x) + 1.f); }

__global__ void k_zero(int* __restrict__ p, int n) {
  int i = blockIdx.x * blockDim.x + threadIdx.x;
  if (i < n) p[i] = 0;
}

__global__ void k_hist(const int* __restrict__ src, const int* __restrict__ dst,
                       const float* __restrict__ w, float* __restrict__ deg,
                       int* __restrict__ cnt) {
  int e = blockIdx.x * 256 + threadIdx.x;
  if (e >= NE) return;
  atomicAdd(&deg[src[e]], w[e]);
  atomicAdd(&cnt[dst[e]], 1);
}

// phase A: per-block (1024) local inclusive scan -> rowptr[i+1]; block sum -> bsum
__global__ __launch_bounds__(1024) void k_scanA(const int* __restrict__ cnt,
                                                int* __restrict__ rowptr,
                                                int* __restrict__ bsum) {
  __shared__ int wsum[16];
  int t = threadIdx.x, lane = t & 63, w = t >> 6;
  int i = blockIdx.x * 1024 + t;
  int v = (i < NN) ? cnt[i] : 0;
  int val = v;
#pragma unroll
  for (int off = 1; off < 64; off <<= 1) {
    int u = __shfl_up(val, off, 64);
    if (lane >= off) val += u;
  }
  if (lane == 63) wsum[w] = val;
  __syncthreads();
  if (w == 0) {
    int s = (lane < 16) ? wsum[lane] : 0;
#pragma unroll
    for (int off = 1; off < 16; off <<= 1) {
      int u = __shfl_up(s, off, 64);
      if (lane >= off) s += u;
    }
    if (lane < 16) wsum[lane] = s;
  }
  __syncthreads();
  int incl = ((w > 0) ? wsum[w - 1] : 0) + val;
  if (i < NN) rowptr[i + 1] = incl;
  if (t == 1023) bsum[blockIdx.x] = incl;
}

// phase B: one wave scans block sums -> exclusive offsets (in place)
__global__ void k_scanB(int* __restrict__ bsum, int* __restrict__ rowptr, int nblk) {
  int lane = threadIdx.x;
  int v = (lane < nblk) ? bsum[lane] : 0;
  int val = v;
#pragma unroll
  for (int off = 1; off < 64; off <<= 1) {
    int u = __shfl_up(val, off, 64);
    if (lane >= off) val += u;
  }
  if (lane < nblk) bsum[lane] = val - v;  // exclusive
  if (lane == 0) rowptr[0] = 0;
}

// phase C: add block offset; fill = exclusive per-node start
__global__ __launch_bounds__(1024) void k_scanC(const int* __restrict__ cnt,
                                                int* __restrict__ rowptr,
                                                int* __restrict__ fill,
                                                const int* __restrict__ bsum) {
  int i = blockIdx.x * 1024 + threadIdx.x;
  if (i >= NN) return;
  int r = rowptr[i + 1] + bsum[blockIdx.x];
  rowptr[i + 1] = r;
  fill[i] = r - cnt[i];
}

// weights -> bf16 Wb[col][kk]; also combined bias[256]
__global__ void k_wconv(const float* __restrict__ Wx, const float* __restrict__ Wh,
                        const float* __restrict__ bx, const float* __restrict__ bh,
                        const float* __restrict__ bg,
                        unsigned short* __restrict__ Wb, float* __restrict__ bias) {
  int idx = blockIdx.x * 256 + threadIdx.x;
  if (idx < 256) bias[idx] = bx[idx] + bh[idx] + bg[idx];
  if (idx >= 256 * 384) return;
  int col = idx / 384;
  int kk = idx - col * 384;
  int g = col >> 6, cc = col & 63;
  int seg = kk >> 6, k = kk & 63;
  float v = (seg < 3) ? Wx[((g * 3 + seg) * 64 + k) * 64 + cc]
                      : Wh[((g * 3 + (seg - 3)) * 64 + k) * 64 + cc];
  Wb[idx] = f2bf(v);
}

// X,H fp32 -> bf16
__global__ void k_cvt(const float* __restrict__ X, const float* __restrict__ H,
                      unsigned short* __restrict__ Xb, unsigned short* __restrict__ Hb) {
  int i = (blockIdx.x * 256 + threadIdx.x) * 4;
  if (i >= NN * 64) return;
  float4 x = *(const float4*)&X[i];
  float4 h = *(const float4*)&H[i];
  *(ushort4*)&Xb[i] = make_ushort4(f2bf(x.x), f2bf(x.y), f2bf(x.z), f2bf(x.w));
  *(ushort4*)&Hb[i] = make_ushort4(f2bf(h.x), f2bf(h.y), f2bf(h.z), f2bf(h.w));
}

__global__ void k_scatter(const int* __restrict__ src, const int* __restrict__ dst,
                          const float* __restrict__ wgt, const float* __restrict__ deg,
                          int* __restrict__ fill, float2* __restrict__ elist) {
  int e = blockIdx.x * 256 + threadIdx.x;
  if (e >= NE) return;
  int s = src[e], d = dst[e];
  float ds = deg[s], dd = deg[d];
  float a = (ds > 0.f) ? rsqrtf(ds) : 0.f;
  float b = (dd > 0.f) ? rsqrtf(dd) : 0.f;
  float nm = -a * wgt[e] * b;
  int pos = atomicAdd(&fill[d], 1);
  elist[pos] = make_float2(__int_as_float(s), nm);
}

// bf16 gather prop: 8 lanes/node x 8ch. mode=1: out = 2*acc - base (Cheb T2)
__global__ __launch_bounds__(256) void k_prop(
    const int* __restrict__ rowptr, const float2* __restrict__ elist,
    const unsigned short* __restrict__ inX, const unsigned short* __restrict__ inH,
    unsigned short* __restrict__ outX, unsigned short* __restrict__ outH,
    const unsigned short* __restrict__ baseX, const unsigned short* __restrict__ baseH,
    int mode) {
  int n = blockIdx.x * 32 + (threadIdx.x >> 3);
  int q = (threadIdx.x & 7) * 8;
  if (n >= NN) return;
  int beg = rowptr[n], end = rowptr[n + 1];
  float ax[8], ah[8];
#pragma unroll
  for (int j = 0; j < 8; ++j) { ax[j] = 0.f; ah[j] = 0.f; }
  int i = beg;
  for (; i + 1 < end; i += 2) {
    float2 e0 = elist[i], e1 = elist[i + 1];
    int s0 = __float_as_int(e0.x), s1 = __float_as_int(e1.x);
    ushort8 x0 = *(const ushort8*)&inX[s0 * 64 + q];
    ushort8 h0 = *(const ushort8*)&inH[s0 * 64 + q];
    ushort8 x1 = *(const ushort8*)&inX[s1 * 64 + q];
    ushort8 h1 = *(const ushort8*)&inH[s1 * 64 + q];
#pragma unroll
    for (int j = 0; j < 8; ++j) {
      ax[j] += e0.y * bf2f(x0[j]) + e1.y * bf2f(x1[j]);
      ah[j] += e0.y * bf2f(h0[j]) + e1.y * bf2f(h1[j]);
    }
  }
  if (i < end) {
    float2 e0 = elist[i];
    int s0 = __float_as_int(e0.x);
    ushort8 x0 = *(const ushort8*)&inX[s0 * 64 + q];
    ushort8 h0 = *(const ushort8*)&inH[s0 * 64 + q];
#pragma unroll
    for (int j = 0; j < 8; ++j) {
      ax[j] += e0.y * bf2f(x0[j]);
      ah[j] += e0.y * bf2f(h0[j]);
    }
  }
  ushort8 ox, oh;
  if (mode) {
    ushort8 bx8 = *(const ushort8*)&baseX[n * 64 + q];
    ushort8 bh8 = *(const ushort8*)&baseH[n * 64 + q];
#pragma unroll
    for (int j = 0; j < 8; ++j) {
      ox[j] = f2bf(2.f * ax[j] - bf2f(bx8[j]));
      oh[j] = f2bf(2.f * ah[j] - bf2f(bh8[j]));
    }
  } else {
#pragma unroll
    for (int j = 0; j < 8; ++j) { ox[j] = f2bf(ax[j]); oh[j] = f2bf(ah[j]); }
  }
  *(ushort8*)&outX[n * 64 + q] = ox;
  *(ushort8*)&outH[n * 64 + q] = oh;
}

// barrier-free MFMA gates: 1 wave/block, 32 rows x 256 cols, all in registers.
__global__ __launch_bounds__(64) void k_gates(
    const unsigned short* __restrict__ Xb, const unsigned short* __restrict__ Hb,
    const unsigned short* __restrict__ T1X, const unsigned short* __restrict__ T1H,
    const unsigned short* __restrict__ T2X, const unsigned short* __restrict__ T2H,
    const unsigned short* __restrict__ Wb, const float* __restrict__ C,
    const float* __restrict__ bias, const float* __restrict__ wc,
    float* __restrict__ out) {
  const int l = threadIdx.x;
  const int wbase = blockIdx.x * 32;
  const int lr = l & 15;
  const int lk = (l >> 4) * 8;

  f32x4 acc[2][16];
#pragma unroll
  for (int rb = 0; rb < 2; ++rb)
#pragma unroll
    for (int cf = 0; cf < 16; ++cf) acc[rb][cf] = (f32x4){0.f, 0.f, 0.f, 0.f};

  int r0 = wbase + lr, r1 = wbase + 16 + lr;
  int r0c = (r0 < NN) ? r0 : NN - 1;
  int r1c = (r1 < NN) ? r1 : NN - 1;

  const unsigned short* segp[6] = {Xb, T1X, T2X, Hb, T1H, T2H};
#pragma unroll
  for (int seg = 0; seg < 6; ++seg) {
    const unsigned short* sp = segp[seg];
#pragma unroll
    for (int h = 0; h < 2; ++h) {
      const int kc = seg * 2 + h;
      const int ko = h * 32 + lk;
      short8 a0 = *(const short8*)&sp[r0c * 64 + ko];
      short8 a1 = *(const short8*)&sp[r1c * 64 + ko];
#pragma unroll
      for (int cf = 0; cf < 16; ++cf) {
        short8 b = *(const short8*)&Wb[(cf * 16 + lr) * 384 + kc * 32 + lk];
        acc[0][cf] = __builtin_amdgcn_mfma_f32_16x16x32_bf16(a0, b, acc[0][cf], 0, 0, 0);
        acc[1][cf] = __builtin_amdgcn_mfma_f32_16x16x32_bf16(a1, b, acc[1][cf], 0, 0, 0);
      }
    }
  }

  // epilogue fully in registers: row=(l>>4)*4+q (+16*rb), col=cf*16+(l&15)
#pragma unroll
  for (int rb = 0; rb < 2; ++rb) {
#pragma unroll
    for (int q = 0; q < 4; ++q) {
      int n = wbase + rb * 16 + (l >> 4) * 4 + q;
      if (n >= NN) continue;
#pragma unroll
      for (int cq = 0; cq < 4; ++cq) {
        int cc = cq * 16 + lr;
        float cv = C[n * 64 + cc];
        float pI = acc[rb][cq][q]      + bias[cc]       + wc[cc] * cv;
        float pF = acc[rb][4 + cq][q]  + bias[64 + cc]  + wc[64 + cc] * cv;
        float pT = acc[rb][8 + cq][q]  + bias[128 + cc];
        float I = sigm(pI);
        float F = sigm(pF);
        float T = tanh_(pT);
        float Cn = F * cv + I * T;
        float pO = acc[rb][12 + cq][q] + bias[192 + cc] + wc[128 + cc] * Cn;
        float O = sigm(pO);
        out[n * 64 + cc] = O * tanh_(Cn);
        out[NN * 64 + n * 64 + cc] = Cn;
      }
    }
  }
}

extern "C" void kernel_launch(void* const* d_in, const int* in_sizes, int n_in,
                              void* d_out, int out_size, void* d_ws, size_t ws_size,
                              hipStream_t stream) {
  const float* X  = (const float*)d_in[0];
  const int*   ei = (const int*)d_in[1];
  const float* ew = (const float*)d_in[2];
  const float* H  = (const float*)d_in[3];
  const float* C  = (const float*)d_in[4];
  const float* Wx = (const float*)d_in[5];
  const float* bx = (const float*)d_in[6];
  const float* Wh = (const float*)d_in[7];
  const float* bh = (const float*)d_in[8];
  const float* wc = (const float*)d_in[9];
  const float* bg = (const float*)d_in[10];
  float* out = (float*)d_out;
  float* ws = (float*)d_ws;

  const int* src = ei;
  const int* dst = ei + NE;
  float* deg = ws + OFF_DEG;
  int* cnt = (int*)(ws + OFF_CNT);
  int* rowptr = (int*)(ws + OFF_ROWPTR);
  int* fill = (int*)(ws + OFF_FILL);
  int* bsum = (int*)(ws + OFF_BSUM);
  unsigned short* Wb = (unsigned short*)(ws + OFF_WB);
  float* bias = ws + OFF_BIAS;
  float2* elist = (float2*)(ws + OFF_ELIST);
  unsigned short* Xb  = (unsigned short*)(ws + OFF_XB);
  unsigned short* Hb  = (unsigned short*)(ws + OFF_HB);
  unsigned short* T1X = (unsigned short*)(ws + OFF_T1X);
  unsigned short* T1H = (unsigned short*)(ws + OFF_T1H);
  unsigned short* T2X = (unsigned short*)(ws + OFF_T2X);
  unsigned short* T2H = (unsigned short*)(ws + OFF_T2H);

  const int NBLK = (NN + 1023) / 1024;  // 49

  k_zero<<<(100000 + 255) / 256, 256, 0, stream>>>((int*)ws, 100000);
  k_hist<<<(NE + 255) / 256, 256, 0, stream>>>(src, dst, ew, deg, cnt);
  k_scanA<<<NBLK, 1024, 0, stream>>>(cnt, rowptr, bsum);
  k_scanB<<<1, 64, 0, stream>>>(bsum, rowptr, NBLK);
  k_scanC<<<NBLK, 1024, 0, stream>>>(cnt, rowptr, fill, bsum);
  k_wconv<<<(256 * 384 + 255) / 256, 256, 0, stream>>>(Wx, Wh, bx, bh, bg, Wb, bias);
  k_cvt<<<(NN * 64 / 4 + 255) / 256, 256, 0, stream>>>(X, H, Xb, Hb);
  k_scatter<<<(NE + 255) / 256, 256, 0, stream>>>(src, dst, ew, deg, fill, elist);
  k_prop<<<(NN + 31) / 32, 256, 0, stream>>>(rowptr, elist, Xb, Hb, T1X, T1H,
                                             nullptr, nullptr, 0);
  k_prop<<<(NN + 31) / 32, 256, 0, stream>>>(rowptr, elist, T1X, T1H, T2X, T2H,
                                             Xb, Hb, 1);
  k_gates<<<(NN + 31) / 32, 64, 0, stream>>>(Xb, Hb, T1X, T1H, T2X, T2H,
                                             Wb, C, bias, wc, out);
}

// Round 4
// 311.246 us; speedup vs baseline: 1.7863x; 1.1280x over previous
//
#include <hip/hip_runtime.h>
#include <math.h>

#define NN 50000
#define NE 800000

typedef __attribute__((ext_vector_type(8))) short short8;
typedef __attribute__((ext_vector_type(8))) unsigned short ushort8;
typedef __attribute__((ext_vector_type(4))) float f32x4;

// workspace layout (offsets in 4-byte words)
#define OFF_DEG    0          // float[NN]
#define OFF_CNT    50000      // int[NN]
#define OFF_ROWPTR 100000     // int[NN+1] (pad to 50008)
#define OFF_FILL   150008     // int[NN]
#define OFF_BSUM   200008     // int[64]
#define OFF_WB     200072     // ushort[256*384] = 49152 words
#define OFF_BIAS   249224     // float[256] combined bx+bh+bg
#define OFF_ELIST  249480     // float2[NE] (even offset -> 8B aligned)
#define OFF_XB     1849480    // ushort[NN*64] = 1.6M words each
#define OFF_HB     3449480
#define OFF_T1X    5049480
#define OFF_T1H    6649480
#define OFF_T2X    8249480
#define OFF_T2H    9849480

__device__ inline unsigned short f2bf(float f) {
  union { float f; unsigned u; } v; v.f = f;
  unsigned u = v.u;
  return (unsigned short)((u + 0x7FFFu + ((u >> 16) & 1u)) >> 16);
}
__device__ inline float bf2f(unsigned short u) {
  return __uint_as_float(((unsigned)u) << 16);
}
__device__ inline float sigm(float x) { return 1.f / (1.f + __expf(-x)); }
__device__ inline float tanh_(float x) { return 1.f - 2.f / (__expf(2.f * x) + 1.f); }

__global__ void k_zero(int* __restrict__ p, int n) {
  int i = blockIdx.x * blockDim.x + threadIdx.x;
  if (i < n) p[i] = 0;
}

__global__ void k_hist(const int* __restrict__ src, const int* __restrict__ dst,
                       const float* __restrict__ w, float* __restrict__ deg,
                       int* __restrict__ cnt) {
  int e = blockIdx.x * 256 + threadIdx.x;
  if (e >= NE) return;
  atomicAdd(&deg[src[e]], w[e]);
  atomicAdd(&cnt[dst[e]], 1);
}

// phase A: per-block (1024) local inclusive scan -> rowptr[i+1]; block sum -> bsum
__global__ __launch_bounds__(1024) void k_scanA(const int* __restrict__ cnt,
                                                int* __restrict__ rowptr,
                                                int* __restrict__ bsum) {
  __shared__ int wsum[16];
  int t = threadIdx.x, lane = t & 63, w = t >> 6;
  int i = blockIdx.x * 1024 + t;
  int v = (i < NN) ? cnt[i] : 0;
  int val = v;
#pragma unroll
  for (int off = 1; off < 64; off <<= 1) {
    int u = __shfl_up(val, off, 64);
    if (lane >= off) val += u;
  }
  if (lane == 63) wsum[w] = val;
  __syncthreads();
  if (w == 0) {
    int s = (lane < 16) ? wsum[lane] : 0;
#pragma unroll
    for (int off = 1; off < 16; off <<= 1) {
      int u = __shfl_up(s, off, 64);
      if (lane >= off) s += u;
    }
    if (lane < 16) wsum[lane] = s;
  }
  __syncthreads();
  int incl = ((w > 0) ? wsum[w - 1] : 0) + val;
  if (i < NN) rowptr[i + 1] = incl;
  if (t == 1023) bsum[blockIdx.x] = incl;
}

__global__ void k_scanB(int* __restrict__ bsum, int* __restrict__ rowptr, int nblk) {
  int lane = threadIdx.x;
  int v = (lane < nblk) ? bsum[lane] : 0;
  int val = v;
#pragma unroll
  for (int off = 1; off < 64; off <<= 1) {
    int u = __shfl_up(val, off, 64);
    if (lane >= off) val += u;
  }
  if (lane < nblk) bsum[lane] = val - v;  // exclusive
  if (lane == 0) rowptr[0] = 0;
}

__global__ __launch_bounds__(1024) void k_scanC(const int* __restrict__ cnt,
                                                int* __restrict__ rowptr,
                                                int* __restrict__ fill,
                                                const int* __restrict__ bsum) {
  int i = blockIdx.x * 1024 + threadIdx.x;
  if (i >= NN) return;
  int r = rowptr[i + 1] + bsum[blockIdx.x];
  rowptr[i + 1] = r;
  fill[i] = r - cnt[i];
}

// weights -> bf16 Wb[col][kk]; also combined bias[256]
__global__ void k_wconv(const float* __restrict__ Wx, const float* __restrict__ Wh,
                        const float* __restrict__ bx, const float* __restrict__ bh,
                        const float* __restrict__ bg,
                        unsigned short* __restrict__ Wb, float* __restrict__ bias) {
  int idx = blockIdx.x * 256 + threadIdx.x;
  if (idx < 256) bias[idx] = bx[idx] + bh[idx] + bg[idx];
  if (idx >= 256 * 384) return;
  int col = idx / 384;
  int kk = idx - col * 384;
  int g = col >> 6, cc = col & 63;
  int seg = kk >> 6, k = kk & 63;
  float v = (seg < 3) ? Wx[((g * 3 + seg) * 64 + k) * 64 + cc]
                      : Wh[((g * 3 + (seg - 3)) * 64 + k) * 64 + cc];
  Wb[idx] = f2bf(v);
}

__global__ void k_cvt(const float* __restrict__ X, const float* __restrict__ H,
                      unsigned short* __restrict__ Xb, unsigned short* __restrict__ Hb) {
  int i = (blockIdx.x * 256 + threadIdx.x) * 4;
  if (i >= NN * 64) return;
  float4 x = *(const float4*)&X[i];
  float4 h = *(const float4*)&H[i];
  *(ushort4*)&Xb[i] = make_ushort4(f2bf(x.x), f2bf(x.y), f2bf(x.z), f2bf(x.w));
  *(ushort4*)&Hb[i] = make_ushort4(f2bf(h.x), f2bf(h.y), f2bf(h.z), f2bf(h.w));
}

__global__ void k_scatter(const int* __restrict__ src, const int* __restrict__ dst,
                          const float* __restrict__ wgt, const float* __restrict__ deg,
                          int* __restrict__ fill, float2* __restrict__ elist) {
  int e = blockIdx.x * 256 + threadIdx.x;
  if (e >= NE) return;
  int s = src[e], d = dst[e];
  float ds = deg[s], dd = deg[d];
  float a = (ds > 0.f) ? rsqrtf(ds) : 0.f;
  float b = (dd > 0.f) ? rsqrtf(dd) : 0.f;
  float nm = -a * wgt[e] * b;
  int pos = atomicAdd(&fill[d], 1);
  elist[pos] = make_float2(__int_as_float(s), nm);
}

// bf16 gather prop, 4-edge unroll: 8 lanes/node x 8ch. mode=1: out = 2*acc - base
__global__ __launch_bounds__(256) void k_prop(
    const int* __restrict__ rowptr, const float2* __restrict__ elist,
    const unsigned short* __restrict__ inX, const unsigned short* __restrict__ inH,
    unsigned short* __restrict__ outX, unsigned short* __restrict__ outH,
    const unsigned short* __restrict__ baseX, const unsigned short* __restrict__ baseH,
    int mode) {
  int n = blockIdx.x * 32 + (threadIdx.x >> 3);
  int q = (threadIdx.x & 7) * 8;
  if (n >= NN) return;
  int beg = rowptr[n], end = rowptr[n + 1];
  float ax[8], ah[8];
#pragma unroll
  for (int j = 0; j < 8; ++j) { ax[j] = 0.f; ah[j] = 0.f; }
  int i = beg;
  for (; i + 3 < end; i += 4) {
    float2 e0 = elist[i], e1 = elist[i + 1], e2 = elist[i + 2], e3 = elist[i + 3];
    int s0 = __float_as_int(e0.x), s1 = __float_as_int(e1.x);
    int s2 = __float_as_int(e2.x), s3 = __float_as_int(e3.x);
    ushort8 x0 = *(const ushort8*)&inX[s0 * 64 + q];
    ushort8 x1 = *(const ushort8*)&inX[s1 * 64 + q];
    ushort8 x2 = *(const ushort8*)&inX[s2 * 64 + q];
    ushort8 x3 = *(const ushort8*)&inX[s3 * 64 + q];
    ushort8 h0 = *(const ushort8*)&inH[s0 * 64 + q];
    ushort8 h1 = *(const ushort8*)&inH[s1 * 64 + q];
    ushort8 h2 = *(const ushort8*)&inH[s2 * 64 + q];
    ushort8 h3 = *(const ushort8*)&inH[s3 * 64 + q];
#pragma unroll
    for (int j = 0; j < 8; ++j) {
      ax[j] += e0.y * bf2f(x0[j]) + e1.y * bf2f(x1[j]) +
               e2.y * bf2f(x2[j]) + e3.y * bf2f(x3[j]);
      ah[j] += e0.y * bf2f(h0[j]) + e1.y * bf2f(h1[j]) +
               e2.y * bf2f(h2[j]) + e3.y * bf2f(h3[j]);
    }
  }
  for (; i < end; ++i) {
    float2 e0 = elist[i];
    int s0 = __float_as_int(e0.x);
    ushort8 x0 = *(const ushort8*)&inX[s0 * 64 + q];
    ushort8 h0 = *(const ushort8*)&inH[s0 * 64 + q];
#pragma unroll
    for (int j = 0; j < 8; ++j) {
      ax[j] += e0.y * bf2f(x0[j]);
      ah[j] += e0.y * bf2f(h0[j]);
    }
  }
  ushort8 ox, oh;
  if (mode) {
    ushort8 bx8 = *(const ushort8*)&baseX[n * 64 + q];
    ushort8 bh8 = *(const ushort8*)&baseH[n * 64 + q];
#pragma unroll
    for (int j = 0; j < 8; ++j) {
      ox[j] = f2bf(2.f * ax[j] - bf2f(bx8[j]));
      oh[j] = f2bf(2.f * ah[j] - bf2f(bh8[j]));
    }
  } else {
#pragma unroll
    for (int j = 0; j < 8; ++j) { ox[j] = f2bf(ax[j]); oh[j] = f2bf(ah[j]); }
  }
  *(ushort8*)&outX[n * 64 + q] = ox;
  *(ushort8*)&outH[n * 64 + q] = oh;
}

// MFMA gates v3: 256 thr / 4 waves; block = 32 rows; wave w = gate w
// (32 rows x 64 cols per wave, acc = 32 VGPRs). LDS exchange for epilogue.
#define PSTR 264  // pre[] row stride (264 % 32 == 8 -> 2-way banks, free)
__global__ __launch_bounds__(256, 4) void k_gates(
    const unsigned short* __restrict__ Xb, const unsigned short* __restrict__ Hb,
    const unsigned short* __restrict__ T1X, const unsigned short* __restrict__ T1H,
    const unsigned short* __restrict__ T2X, const unsigned short* __restrict__ T2H,
    const unsigned short* __restrict__ Wb, const float* __restrict__ C,
    const float* __restrict__ bias, const float* __restrict__ wc,
    float* __restrict__ out) {
  __shared__ float pre[32 * PSTR];  // 33792 B
  const int t = threadIdx.x;
  const int wv = t >> 6;         // gate
  const int l = t & 63;
  const int base = blockIdx.x * 32;
  const int lr = l & 15;
  const int lk = (l >> 4) * 8;

  f32x4 acc[2][4];
#pragma unroll
  for (int rb = 0; rb < 2; ++rb)
#pragma unroll
    for (int cf = 0; cf < 4; ++cf) acc[rb][cf] = (f32x4){0.f, 0.f, 0.f, 0.f};

  int r0 = base + lr, r1 = base + 16 + lr;
  int r0c = (r0 < NN) ? r0 : NN - 1;
  int r1c = (r1 < NN) ? r1 : NN - 1;

  const unsigned short* segp[6] = {Xb, T1X, T2X, Hb, T1H, T2H};
#pragma unroll
  for (int seg = 0; seg < 6; ++seg) {
    const unsigned short* sp = segp[seg];
#pragma unroll
    for (int h = 0; h < 2; ++h) {
      const int kc = seg * 2 + h;
      const int ko = h * 32 + lk;
      short8 a0 = *(const short8*)&sp[r0c * 64 + ko];
      short8 a1 = *(const short8*)&sp[r1c * 64 + ko];
#pragma unroll
      for (int cf = 0; cf < 4; ++cf) {
        short8 b = *(const short8*)&Wb[(wv * 64 + cf * 16 + lr) * 384 + kc * 32 + lk];
        acc[0][cf] = __builtin_amdgcn_mfma_f32_16x16x32_bf16(a0, b, acc[0][cf], 0, 0, 0);
        acc[1][cf] = __builtin_amdgcn_mfma_f32_16x16x32_bf16(a1, b, acc[1][cf], 0, 0, 0);
      }
    }
  }

  // exchange: pre[row][wv*64 + cf*16 + lr]
#pragma unroll
  for (int rb = 0; rb < 2; ++rb)
#pragma unroll
    for (int cf = 0; cf < 4; ++cf)
#pragma unroll
      for (int qq = 0; qq < 4; ++qq) {
        int row = rb * 16 + (l >> 4) * 4 + qq;
        pre[row * PSTR + wv * 64 + cf * 16 + lr] = acc[rb][cf][qq];
      }
  __syncthreads();

  // fused gate epilogue
  for (int i = t; i < 32 * 64; i += 256) {
    int m = i >> 6;
    int cc = i & 63;
    int n = base + m;
    if (n >= NN) continue;
    const float* pr = &pre[m * PSTR];
    float cv = C[n * 64 + cc];
    float pI = pr[cc]        + bias[cc]        + wc[cc] * cv;
    float pF = pr[64 + cc]   + bias[64 + cc]   + wc[64 + cc] * cv;
    float pT = pr[128 + cc]  + bias[128 + cc];
    float I = sigm(pI);
    float F = sigm(pF);
    float T = tanh_(pT);
    float Cn = F * cv + I * T;
    float pO = pr[192 + cc]  + bias[192 + cc]  + wc[128 + cc] * Cn;
    float O = sigm(pO);
    out[n * 64 + cc] = O * tanh_(Cn);
    out[NN * 64 + n * 64 + cc] = Cn;
  }
}

extern "C" void kernel_launch(void* const* d_in, const int* in_sizes, int n_in,
                              void* d_out, int out_size, void* d_ws, size_t ws_size,
                              hipStream_t stream) {
  const float* X  = (const float*)d_in[0];
  const int*   ei = (const int*)d_in[1];
  const float* ew = (const float*)d_in[2];
  const float* H  = (const float*)d_in[3];
  const float* C  = (const float*)d_in[4];
  const float* Wx = (const float*)d_in[5];
  const float* bx = (const float*)d_in[6];
  const float* Wh = (const float*)d_in[7];
  const float* bh = (const float*)d_in[8];
  const float* wc = (const float*)d_in[9];
  const float* bg = (const float*)d_in[10];
  float* out = (float*)d_out;
  float* ws = (float*)d_ws;

  const int* src = ei;
  const int* dst = ei + NE;
  float* deg = ws + OFF_DEG;
  int* cnt = (int*)(ws + OFF_CNT);
  int* rowptr = (int*)(ws + OFF_ROWPTR);
  int* fill = (int*)(ws + OFF_FILL);
  int* bsum = (int*)(ws + OFF_BSUM);
  unsigned short* Wb = (unsigned short*)(ws + OFF_WB);
  float* bias = ws + OFF_BIAS;
  float2* elist = (float2*)(ws + OFF_ELIST);
  unsigned short* Xb  = (unsigned short*)(ws + OFF_XB);
  unsigned short* Hb  = (unsigned short*)(ws + OFF_HB);
  unsigned short* T1X = (unsigned short*)(ws + OFF_T1X);
  unsigned short* T1H = (unsigned short*)(ws + OFF_T1H);
  unsigned short* T2X = (unsigned short*)(ws + OFF_T2X);
  unsigned short* T2H = (unsigned short*)(ws + OFF_T2H);

  const int NBLK = (NN + 1023) / 1024;  // 49

  k_zero<<<(100000 + 255) / 256, 256, 0, stream>>>((int*)ws, 100000);
  k_hist<<<(NE + 255) / 256, 256, 0, stream>>>(src, dst, ew, deg, cnt);
  k_scanA<<<NBLK, 1024, 0, stream>>>(cnt, rowptr, bsum);
  k_scanB<<<1, 64, 0, stream>>>(bsum, rowptr, NBLK);
  k_scanC<<<NBLK, 1024, 0, stream>>>(cnt, rowptr, fill, bsum);
  k_wconv<<<(256 * 384 + 255) / 256, 256, 0, stream>>>(Wx, Wh, bx, bh, bg, Wb, bias);
  k_cvt<<<(NN * 64 / 4 + 255) / 256, 256, 0, stream>>>(X, H, Xb, Hb);
  k_scatter<<<(NE + 255) / 256, 256, 0, stream>>>(src, dst, ew, deg, fill, elist);
  k_prop<<<(NN + 31) / 32, 256, 0, stream>>>(rowptr, elist, Xb, Hb, T1X, T1H,
                                             nullptr, nullptr, 0);
  k_prop<<<(NN + 31) / 32, 256, 0, stream>>>(rowptr, elist, T1X, T1H, T2X, T2H,
                                             Xb, Hb, 1);
  k_gates<<<(NN + 31) / 32, 256, 0, stream>>>(Xb, Hb, T1X, T1H, T2X, T2H,
                                              Wb, C, bias, wc, out);
}

// Round 5
// 275.748 us; speedup vs baseline: 2.0163x; 1.1287x over previous
//
#include <hip/hip_runtime.h>
#include <math.h>

#define NN 50000
#define NE 800000

typedef __attribute__((ext_vector_type(8))) short short8;
typedef __attribute__((ext_vector_type(4))) float f32x4;

// workspace layout (offsets in 4-byte words)
#define OFF_DEG    0          // float[NN] -> becomes dinv after k_scanC
#define OFF_CNT    50000      // int[NN]
#define OFF_ROWPTR 100000     // int[NN+1]
#define OFF_FILL   150008     // (unused)
#define OFF_BSUM   200008     // int[64]
#define OFF_WB     200072     // ushort[256*384] = 49152 words
#define OFF_BIAS   249224     // float[256]
#define OFF_ELIST  249480     // uint[NE] = 800000 words (packed src|bf16norm)
#define OFF_RANK   1049480    // int[NE] = 800000 words
#define OFF_XB     1849480    // ushort[NN*64] = 1.6M words each
#define OFF_HB     3449480
#define OFF_T1X    5049480
#define OFF_T1H    6649480
#define OFF_T2X    8249480
#define OFF_T2H    9849480

__device__ inline unsigned short f2bf(float f) {
  union { float f; unsigned u; } v; v.f = f;
  unsigned u = v.u;
  return (unsigned short)((u + 0x7FFFu + ((u >> 16) & 1u)) >> 16);
}
__device__ inline float bf2f(unsigned short u) {
  return __uint_as_float(((unsigned)u) << 16);
}
__device__ inline float sigm(float x) { return 1.f / (1.f + __expf(-x)); }
__device__ inline float tanh_(float x) { return 1.f - 2.f / (__expf(2.f * x) + 1.f); }

__global__ void k_zero(int* __restrict__ p, int n) {
  int i = blockIdx.x * blockDim.x + threadIdx.x;
  if (i < n) p[i] = 0;
}

// histogram + per-edge rank (atomic return value)
__global__ void k_hist(const int* __restrict__ src, const int* __restrict__ dst,
                       const float* __restrict__ w, float* __restrict__ deg,
                       int* __restrict__ cnt, int* __restrict__ rank) {
  int e = blockIdx.x * 256 + threadIdx.x;
  if (e >= NE) return;
  rank[e] = atomicAdd(&cnt[dst[e]], 1);
  atomicAdd(&deg[src[e]], w[e]);
}

// phase A: per-block (1024) local inclusive scan -> rowptr[i+1]; block sum -> bsum
__global__ __launch_bounds__(1024) void k_scanA(const int* __restrict__ cnt,
                                                int* __restrict__ rowptr,
                                                int* __restrict__ bsum) {
  __shared__ int wsum[16];
  int t = threadIdx.x, lane = t & 63, w = t >> 6;
  int i = blockIdx.x * 1024 + t;
  int v = (i < NN) ? cnt[i] : 0;
  int val = v;
#pragma unroll
  for (int off = 1; off < 64; off <<= 1) {
    int u = __shfl_up(val, off, 64);
    if (lane >= off) val += u;
  }
  if (lane == 63) wsum[w] = val;
  __syncthreads();
  if (w == 0) {
    int s = (lane < 16) ? wsum[lane] : 0;
#pragma unroll
    for (int off = 1; off < 16; off <<= 1) {
      int u = __shfl_up(s, off, 64);
      if (lane >= off) s += u;
    }
    if (lane < 16) wsum[lane] = s;
  }
  __syncthreads();
  int incl = ((w > 0) ? wsum[w - 1] : 0) + val;
  if (i < NN) rowptr[i + 1] = incl;
  if (t == 1023) bsum[blockIdx.x] = incl;
}

__global__ void k_scanB(int* __restrict__ bsum, int* __restrict__ rowptr, int nblk) {
  int lane = threadIdx.x;
  int v = (lane < nblk) ? bsum[lane] : 0;
  int val = v;
#pragma unroll
  for (int off = 1; off < 64; off <<= 1) {
    int u = __shfl_up(val, off, 64);
    if (lane >= off) val += u;
  }
  if (lane < nblk) bsum[lane] = val - v;  // exclusive
  if (lane == 0) rowptr[0] = 0;
}

// phase C: finalize rowptr; also deg -> dinv in place
__global__ __launch_bounds__(1024) void k_scanC(int* __restrict__ rowptr,
                                                const int* __restrict__ bsum,
                                                float* __restrict__ deg) {
  int i = blockIdx.x * 1024 + threadIdx.x;
  if (i >= NN) return;
  rowptr[i + 1] += bsum[blockIdx.x];
  float d = deg[i];
  deg[i] = (d > 0.f) ? rsqrtf(d) : 0.f;
}

// weights -> bf16 Wb[col][kk]; also combined bias[256]
__global__ void k_wconv(const float* __restrict__ Wx, const float* __restrict__ Wh,
                        const float* __restrict__ bx, const float* __restrict__ bh,
                        const float* __restrict__ bg,
                        unsigned short* __restrict__ Wb, float* __restrict__ bias) {
  int idx = blockIdx.x * 256 + threadIdx.x;
  if (idx < 256) bias[idx] = bx[idx] + bh[idx] + bg[idx];
  if (idx >= 256 * 384) return;
  int col = idx / 384;
  int kk = idx - col * 384;
  int g = col >> 6, cc = col & 63;
  int seg = kk >> 6, k = kk & 63;
  float v = (seg < 3) ? Wx[((g * 3 + seg) * 64 + k) * 64 + cc]
                      : Wh[((g * 3 + (seg - 3)) * 64 + k) * 64 + cc];
  Wb[idx] = f2bf(v);
}

__global__ void k_cvt(const float* __restrict__ X, const float* __restrict__ H,
                      unsigned short* __restrict__ Xb, unsigned short* __restrict__ Hb) {
  int i = (blockIdx.x * 256 + threadIdx.x) * 4;
  if (i >= NN * 64) return;
  float4 x = *(const float4*)&X[i];
  float4 h = *(const float4*)&H[i];
  *(ushort4*)&Xb[i] = make_ushort4(f2bf(x.x), f2bf(x.y), f2bf(x.z), f2bf(x.w));
  *(ushort4*)&Hb[i] = make_ushort4(f2bf(h.x), f2bf(h.y), f2bf(h.z), f2bf(h.w));
}

// atomic-free scatter: pos = rowptr[dst] + rank; entry = bf16(norm)<<16 | src
__global__ void k_scatter(const int* __restrict__ src, const int* __restrict__ dst,
                          const float* __restrict__ wgt, const float* __restrict__ dinv,
                          const int* __restrict__ rowptr, const int* __restrict__ rank,
                          unsigned* __restrict__ elist) {
  int e = blockIdx.x * 256 + threadIdx.x;
  if (e >= NE) return;
  int s = src[e], d = dst[e];
  float nm = -dinv[s] * wgt[e] * dinv[d];
  int pos = rowptr[d] + rank[e];
  elist[pos] = (((unsigned)f2bf(nm)) << 16) | (unsigned)s;
}

// wave-per-node prop: 64 lanes = 64 channels, X and H together.
// mode=1: out = 2*acc - base (Chebyshev T2)
__global__ __launch_bounds__(256) void k_prop(
    const int* __restrict__ rowptr, const unsigned* __restrict__ elist,
    const unsigned short* __restrict__ inX, const unsigned short* __restrict__ inH,
    unsigned short* __restrict__ outX, unsigned short* __restrict__ outH,
    const unsigned short* __restrict__ baseX, const unsigned short* __restrict__ baseH,
    int mode) {
  int n = __builtin_amdgcn_readfirstlane(blockIdx.x * 4 + (threadIdx.x >> 6));
  int c = threadIdx.x & 63;
  if (n >= NN) return;
  int beg = rowptr[n], end = rowptr[n + 1];
  float ax = 0.f, ah = 0.f;
  int i = beg;
  for (; i + 3 < end; i += 4) {
    unsigned u0 = elist[i], u1 = elist[i + 1], u2 = elist[i + 2], u3 = elist[i + 3];
    int s0 = (int)(u0 & 0xffffu), s1 = (int)(u1 & 0xffffu);
    int s2 = (int)(u2 & 0xffffu), s3 = (int)(u3 & 0xffffu);
    float n0 = __uint_as_float(u0 & 0xffff0000u);
    float n1 = __uint_as_float(u1 & 0xffff0000u);
    float n2 = __uint_as_float(u2 & 0xffff0000u);
    float n3 = __uint_as_float(u3 & 0xffff0000u);
    float x0 = bf2f(inX[s0 * 64 + c]), h0 = bf2f(inH[s0 * 64 + c]);
    float x1 = bf2f(inX[s1 * 64 + c]), h1 = bf2f(inH[s1 * 64 + c]);
    float x2 = bf2f(inX[s2 * 64 + c]), h2 = bf2f(inH[s2 * 64 + c]);
    float x3 = bf2f(inX[s3 * 64 + c]), h3 = bf2f(inH[s3 * 64 + c]);
    ax += n0 * x0; ah += n0 * h0;
    ax += n1 * x1; ah += n1 * h1;
    ax += n2 * x2; ah += n2 * h2;
    ax += n3 * x3; ah += n3 * h3;
  }
  for (; i < end; ++i) {
    unsigned u0 = elist[i];
    int s0 = (int)(u0 & 0xffffu);
    float n0 = __uint_as_float(u0 & 0xffff0000u);
    ax += n0 * bf2f(inX[s0 * 64 + c]);
    ah += n0 * bf2f(inH[s0 * 64 + c]);
  }
  int o = n * 64 + c;
  if (mode) {
    outX[o] = f2bf(2.f * ax - bf2f(baseX[o]));
    outH[o] = f2bf(2.f * ah - bf2f(baseH[o]));
  } else {
    outX[o] = f2bf(ax);
    outH[o] = f2bf(ah);
  }
}

// MFMA gates: 256 thr / 4 waves; block = 32 rows; wave w = gate w
#define PSTR 264  // pre[] row stride (2-way banks, free)
__global__ __launch_bounds__(256, 4) void k_gates(
    const unsigned short* __restrict__ Xb, const unsigned short* __restrict__ Hb,
    const unsigned short* __restrict__ T1X, const unsigned short* __restrict__ T1H,
    const unsigned short* __restrict__ T2X, const unsigned short* __restrict__ T2H,
    const unsigned short* __restrict__ Wb, const float* __restrict__ C,
    const float* __restrict__ bias, const float* __restrict__ wc,
    float* __restrict__ out) {
  __shared__ float pre[32 * PSTR];  // 33792 B
  const int t = threadIdx.x;
  const int wv = t >> 6;         // gate
  const int l = t & 63;
  const int base = blockIdx.x * 32;
  const int lr = l & 15;
  const int lk = (l >> 4) * 8;

  f32x4 acc[2][4];
#pragma unroll
  for (int rb = 0; rb < 2; ++rb)
#pragma unroll
    for (int cf = 0; cf < 4; ++cf) acc[rb][cf] = (f32x4){0.f, 0.f, 0.f, 0.f};

  int r0 = base + lr, r1 = base + 16 + lr;
  int r0c = (r0 < NN) ? r0 : NN - 1;
  int r1c = (r1 < NN) ? r1 : NN - 1;

  const unsigned short* segp[6] = {Xb, T1X, T2X, Hb, T1H, T2H};
#pragma unroll
  for (int seg = 0; seg < 6; ++seg) {
    const unsigned short* sp = segp[seg];
#pragma unroll
    for (int h = 0; h < 2; ++h) {
      const int kc = seg * 2 + h;
      const int ko = h * 32 + lk;
      short8 a0 = *(const short8*)&sp[r0c * 64 + ko];
      short8 a1 = *(const short8*)&sp[r1c * 64 + ko];
#pragma unroll
      for (int cf = 0; cf < 4; ++cf) {
        short8 b = *(const short8*)&Wb[(wv * 64 + cf * 16 + lr) * 384 + kc * 32 + lk];
        acc[0][cf] = __builtin_amdgcn_mfma_f32_16x16x32_bf16(a0, b, acc[0][cf], 0, 0, 0);
        acc[1][cf] = __builtin_amdgcn_mfma_f32_16x16x32_bf16(a1, b, acc[1][cf], 0, 0, 0);
      }
    }
  }

  // exchange: pre[row][wv*64 + cf*16 + lr]
#pragma unroll
  for (int rb = 0; rb < 2; ++rb)
#pragma unroll
    for (int cf = 0; cf < 4; ++cf)
#pragma unroll
      for (int qq = 0; qq < 4; ++qq) {
        int row = rb * 16 + (l >> 4) * 4 + qq;
        pre[row * PSTR + wv * 64 + cf * 16 + lr] = acc[rb][cf][qq];
      }
  __syncthreads();

  // fused gate epilogue
  for (int i = t; i < 32 * 64; i += 256) {
    int m = i >> 6;
    int cc = i & 63;
    int n = base + m;
    if (n >= NN) continue;
    const float* pr = &pre[m * PSTR];
    float cv = C[n * 64 + cc];
    float pI = pr[cc]        + bias[cc]        + wc[cc] * cv;
    float pF = pr[64 + cc]   + bias[64 + cc]   + wc[64 + cc] * cv;
    float pT = pr[128 + cc]  + bias[128 + cc];
    float I = sigm(pI);
    float F = sigm(pF);
    float T = tanh_(pT);
    float Cn = F * cv + I * T;
    float pO = pr[192 + cc]  + bias[192 + cc]  + wc[128 + cc] * Cn;
    float O = sigm(pO);
    out[n * 64 + cc] = O * tanh_(Cn);
    out[NN * 64 + n * 64 + cc] = Cn;
  }
}

extern "C" void kernel_launch(void* const* d_in, const int* in_sizes, int n_in,
                              void* d_out, int out_size, void* d_ws, size_t ws_size,
                              hipStream_t stream) {
  const float* X  = (const float*)d_in[0];
  const int*   ei = (const int*)d_in[1];
  const float* ew = (const float*)d_in[2];
  const float* H  = (const float*)d_in[3];
  const float* C  = (const float*)d_in[4];
  const float* Wx = (const float*)d_in[5];
  const float* bx = (const float*)d_in[6];
  const float* Wh = (const float*)d_in[7];
  const float* bh = (const float*)d_in[8];
  const float* wc = (const float*)d_in[9];
  const float* bg = (const float*)d_in[10];
  float* out = (float*)d_out;
  float* ws = (float*)d_ws;

  const int* src = ei;
  const int* dst = ei + NE;
  float* deg = ws + OFF_DEG;     // becomes dinv
  int* cnt = (int*)(ws + OFF_CNT);
  int* rowptr = (int*)(ws + OFF_ROWPTR);
  int* bsum = (int*)(ws + OFF_BSUM);
  unsigned short* Wb = (unsigned short*)(ws + OFF_WB);
  float* bias = ws + OFF_BIAS;
  unsigned* elist = (unsigned*)(ws + OFF_ELIST);
  int* rank = (int*)(ws + OFF_RANK);
  unsigned short* Xb  = (unsigned short*)(ws + OFF_XB);
  unsigned short* Hb  = (unsigned short*)(ws + OFF_HB);
  unsigned short* T1X = (unsigned short*)(ws + OFF_T1X);
  unsigned short* T1H = (unsigned short*)(ws + OFF_T1H);
  unsigned short* T2X = (unsigned short*)(ws + OFF_T2X);
  unsigned short* T2H = (unsigned short*)(ws + OFF_T2H);

  const int NBLK = (NN + 1023) / 1024;  // 49

  k_zero<<<(100000 + 255) / 256, 256, 0, stream>>>((int*)ws, 100000);
  k_hist<<<(NE + 255) / 256, 256, 0, stream>>>(src, dst, ew, deg, cnt, rank);
  k_scanA<<<NBLK, 1024, 0, stream>>>(cnt, rowptr, bsum);
  k_scanB<<<1, 64, 0, stream>>>(bsum, rowptr, NBLK);
  k_scanC<<<NBLK, 1024, 0, stream>>>(rowptr, bsum, deg);
  k_wconv<<<(256 * 384 + 255) / 256, 256, 0, stream>>>(Wx, Wh, bx, bh, bg, Wb, bias);
  k_cvt<<<(NN * 64 / 4 + 255) / 256, 256, 0, stream>>>(X, H, Xb, Hb);
  k_scatter<<<(NE + 255) / 256, 256, 0, stream>>>(src, dst, ew, deg, rowptr, rank, elist);
  k_prop<<<NN / 4, 256, 0, stream>>>(rowptr, elist, Xb, Hb, T1X, T1H,
                                     nullptr, nullptr, 0);
  k_prop<<<NN / 4, 256, 0, stream>>>(rowptr, elist, T1X, T1H, T2X, T2H,
                                     Xb, Hb, 1);
  k_gates<<<(NN + 31) / 32, 256, 0, stream>>>(Xb, Hb, T1X, T1H, T2X, T2H,
                                              Wb, C, bias, wc, out);
}

// Round 6
// 274.011 us; speedup vs baseline: 2.0291x; 1.0063x over previous
//
#include <hip/hip_runtime.h>
#include <math.h>

#define NN 50000
#define NE 800000

typedef __attribute__((ext_vector_type(8))) short short8;
typedef __attribute__((ext_vector_type(8))) unsigned short ushort8;
typedef __attribute__((ext_vector_type(4))) float f32x4;

// workspace layout (offsets in 4-byte words)
#define OFF_DEG    0          // float[NN] -> becomes dinv after k_scanC
#define OFF_CNT    50000      // int[NN]
#define OFF_ROWPTR 100000     // int[NN+1]
#define OFF_BSUM   200008     // int[64]
#define OFF_WB     200072     // ushort[256*384] = 49152 words
#define OFF_BIAS   249224     // float[256]
#define OFF_ELIST  249480     // uint[NE] (packed bf16norm<<16 | src)
#define OFF_RANK   1049480    // int[NE]
#define OFF_XB     1849480    // ushort[NN*64] = 1.6M words each
#define OFF_HB     3449480
#define OFF_T1X    5049480
#define OFF_T1H    6649480
#define OFF_T2X    8249480
#define OFF_T2H    9849480

// fused-kernel role split
#define HBLK 391   // hist: 8 edges/thread -> 391*2048 >= NE
#define CBLK 1563  // cvt: 8 ch/thread -> 1563*2048 >= NN*64
#define WBLK 384   // wconv: 256*384/256

__device__ inline unsigned short f2bf(float f) {
  union { float f; unsigned u; } v; v.f = f;
  unsigned u = v.u;
  return (unsigned short)((u + 0x7FFFu + ((u >> 16) & 1u)) >> 16);
}
__device__ inline float bf2f(unsigned short u) {
  return __uint_as_float(((unsigned)u) << 16);
}
__device__ inline float sigm(float x) { return 1.f / (1.f + __expf(-x)); }
__device__ inline float tanh_(float x) { return 1.f - 2.f / (__expf(2.f * x) + 1.f); }

__global__ void k_zero(int* __restrict__ p, int n) {
  int i = blockIdx.x * blockDim.x + threadIdx.x;
  if (i < n) p[i] = 0;
}

// fused: hist (8 edges/thread, batched atomics) + cvt + wconv
__global__ __launch_bounds__(256) void k_hc(
    const int* __restrict__ src, const int* __restrict__ dst,
    const float* __restrict__ w, float* __restrict__ deg,
    int* __restrict__ cnt, int* __restrict__ rank,
    const float* __restrict__ X, const float* __restrict__ H,
    unsigned short* __restrict__ Xb, unsigned short* __restrict__ Hb,
    const float* __restrict__ Wx, const float* __restrict__ Wh,
    const float* __restrict__ bx, const float* __restrict__ bh,
    const float* __restrict__ bg,
    unsigned short* __restrict__ Wb, float* __restrict__ bias) {
  const int bid = blockIdx.x;
  const int t = threadIdx.x;
  if (bid < HBLK) {
    // --- histogram role: 8 edges per thread, batched for MLP ---
    const int e0 = bid * 2048 + t;
    int sA[8], dA[8];
    float wA[8];
#pragma unroll
    for (int j = 0; j < 8; ++j) {
      int e = e0 + j * 256;
      bool ok = (e < NE);
      int ec = ok ? e : 0;
      sA[j] = ok ? src[ec] : -1;
      dA[j] = ok ? dst[ec] : -1;
      wA[j] = ok ? w[ec] : 0.f;
    }
    int rA[8];
#pragma unroll
    for (int j = 0; j < 8; ++j)
      if (dA[j] >= 0) rA[j] = atomicAdd(&cnt[dA[j]], 1);
#pragma unroll
    for (int j = 0; j < 8; ++j)
      if (sA[j] >= 0) atomicAdd(&deg[sA[j]], wA[j]);
#pragma unroll
    for (int j = 0; j < 8; ++j) {
      int e = e0 + j * 256;
      if (e < NE) rank[e] = rA[j];
    }
  } else if (bid < HBLK + CBLK) {
    // --- cvt role: X,H fp32 -> bf16, 8 elems/thread ---
    int i = ((bid - HBLK) * 256 + t) * 8;
    if (i >= NN * 64) return;
    float4 x0 = *(const float4*)&X[i];
    float4 x1 = *(const float4*)&X[i + 4];
    float4 h0 = *(const float4*)&H[i];
    float4 h1 = *(const float4*)&H[i + 4];
    ushort8 xb, hb;
    xb[0] = f2bf(x0.x); xb[1] = f2bf(x0.y); xb[2] = f2bf(x0.z); xb[3] = f2bf(x0.w);
    xb[4] = f2bf(x1.x); xb[5] = f2bf(x1.y); xb[6] = f2bf(x1.z); xb[7] = f2bf(x1.w);
    hb[0] = f2bf(h0.x); hb[1] = f2bf(h0.y); hb[2] = f2bf(h0.z); hb[3] = f2bf(h0.w);
    hb[4] = f2bf(h1.x); hb[5] = f2bf(h1.y); hb[6] = f2bf(h1.z); hb[7] = f2bf(h1.w);
    *(ushort8*)&Xb[i] = xb;
    *(ushort8*)&Hb[i] = hb;
  } else {
    // --- wconv role: weights -> bf16 Wb[col][kk]; combined bias ---
    int idx = (bid - HBLK - CBLK) * 256 + t;
    if (idx < 256) bias[idx] = bx[idx] + bh[idx] + bg[idx];
    if (idx >= 256 * 384) return;
    int col = idx / 384;
    int kk = idx - col * 384;
    int g = col >> 6, cc = col & 63;
    int seg = kk >> 6, k = kk & 63;
    float v = (seg < 3) ? Wx[((g * 3 + seg) * 64 + k) * 64 + cc]
                        : Wh[((g * 3 + (seg - 3)) * 64 + k) * 64 + cc];
    Wb[idx] = f2bf(v);
  }
}

// phase A: per-block (1024) local inclusive scan -> rowptr[i+1]; block sum -> bsum
__global__ __launch_bounds__(1024) void k_scanA(const int* __restrict__ cnt,
                                                int* __restrict__ rowptr,
                                                int* __restrict__ bsum) {
  __shared__ int wsum[16];
  int t = threadIdx.x, lane = t & 63, w = t >> 6;
  int i = blockIdx.x * 1024 + t;
  int v = (i < NN) ? cnt[i] : 0;
  int val = v;
#pragma unroll
  for (int off = 1; off < 64; off <<= 1) {
    int u = __shfl_up(val, off, 64);
    if (lane >= off) val += u;
  }
  if (lane == 63) wsum[w] = val;
  __syncthreads();
  if (w == 0) {
    int s = (lane < 16) ? wsum[lane] : 0;
#pragma unroll
    for (int off = 1; off < 16; off <<= 1) {
      int u = __shfl_up(s, off, 64);
      if (lane >= off) s += u;
    }
    if (lane < 16) wsum[lane] = s;
  }
  __syncthreads();
  int incl = ((w > 0) ? wsum[w - 1] : 0) + val;
  if (i < NN) rowptr[i + 1] = incl;
  if (t == 1023) bsum[blockIdx.x] = incl;
}

__global__ void k_scanB(int* __restrict__ bsum, int* __restrict__ rowptr, int nblk) {
  int lane = threadIdx.x;
  int v = (lane < nblk) ? bsum[lane] : 0;
  int val = v;
#pragma unroll
  for (int off = 1; off < 64; off <<= 1) {
    int u = __shfl_up(val, off, 64);
    if (lane >= off) val += u;
  }
  if (lane < nblk) bsum[lane] = val - v;  // exclusive
  if (lane == 0) rowptr[0] = 0;
}

// phase C: finalize rowptr; also deg -> dinv in place
__global__ __launch_bounds__(1024) void k_scanC(int* __restrict__ rowptr,
                                                const int* __restrict__ bsum,
                                                float* __restrict__ deg) {
  int i = blockIdx.x * 1024 + threadIdx.x;
  if (i >= NN) return;
  rowptr[i + 1] += bsum[blockIdx.x];
  float d = deg[i];
  deg[i] = (d > 0.f) ? rsqrtf(d) : 0.f;
}

// atomic-free scatter: pos = rowptr[dst] + rank; entry = bf16(norm)<<16 | src
__global__ void k_scatter(const int* __restrict__ src, const int* __restrict__ dst,
                          const float* __restrict__ wgt, const float* __restrict__ dinv,
                          const int* __restrict__ rowptr, const int* __restrict__ rank,
                          unsigned* __restrict__ elist) {
  int e = blockIdx.x * 256 + threadIdx.x;
  if (e >= NE) return;
  int s = src[e], d = dst[e];
  float nm = -dinv[s] * wgt[e] * dinv[d];
  int pos = rowptr[d] + rank[e];
  elist[pos] = (((unsigned)f2bf(nm)) << 16) | (unsigned)s;
}

// wave-per-node prop: 64 lanes = 64 channels, X and H together.
// mode=1: out = 2*acc - base (Chebyshev T2)
__global__ __launch_bounds__(256) void k_prop(
    const int* __restrict__ rowptr, const unsigned* __restrict__ elist,
    const unsigned short* __restrict__ inX, const unsigned short* __restrict__ inH,
    unsigned short* __restrict__ outX, unsigned short* __restrict__ outH,
    const unsigned short* __restrict__ baseX, const unsigned short* __restrict__ baseH,
    int mode) {
  int n = __builtin_amdgcn_readfirstlane(blockIdx.x * 4 + (threadIdx.x >> 6));
  int c = threadIdx.x & 63;
  if (n >= NN) return;
  int beg = rowptr[n], end = rowptr[n + 1];
  float ax = 0.f, ah = 0.f;
  int i = beg;
  for (; i + 3 < end; i += 4) {
    unsigned u0 = elist[i], u1 = elist[i + 1], u2 = elist[i + 2], u3 = elist[i + 3];
    int s0 = (int)(u0 & 0xffffu), s1 = (int)(u1 & 0xffffu);
    int s2 = (int)(u2 & 0xffffu), s3 = (int)(u3 & 0xffffu);
    float n0 = __uint_as_float(u0 & 0xffff0000u);
    float n1 = __uint_as_float(u1 & 0xffff0000u);
    float n2 = __uint_as_float(u2 & 0xffff0000u);
    float n3 = __uint_as_float(u3 & 0xffff0000u);
    float x0 = bf2f(inX[s0 * 64 + c]), h0 = bf2f(inH[s0 * 64 + c]);
    float x1 = bf2f(inX[s1 * 64 + c]), h1 = bf2f(inH[s1 * 64 + c]);
    float x2 = bf2f(inX[s2 * 64 + c]), h2 = bf2f(inH[s2 * 64 + c]);
    float x3 = bf2f(inX[s3 * 64 + c]), h3 = bf2f(inH[s3 * 64 + c]);
    ax += n0 * x0; ah += n0 * h0;
    ax += n1 * x1; ah += n1 * h1;
    ax += n2 * x2; ah += n2 * h2;
    ax += n3 * x3; ah += n3 * h3;
  }
  for (; i < end; ++i) {
    unsigned u0 = elist[i];
    int s0 = (int)(u0 & 0xffffu);
    float n0 = __uint_as_float(u0 & 0xffff0000u);
    ax += n0 * bf2f(inX[s0 * 64 + c]);
    ah += n0 * bf2f(inH[s0 * 64 + c]);
  }
  int o = n * 64 + c;
  if (mode) {
    outX[o] = f2bf(2.f * ax - bf2f(baseX[o]));
    outH[o] = f2bf(2.f * ah - bf2f(baseH[o]));
  } else {
    outX[o] = f2bf(ax);
    outH[o] = f2bf(ah);
  }
}

// MFMA gates: 256 thr / 4 waves; block = 32 rows; wave w = gate w
#define PSTR 264  // pre[] row stride (2-way banks, free)
__global__ __launch_bounds__(256, 4) void k_gates(
    const unsigned short* __restrict__ Xb, const unsigned short* __restrict__ Hb,
    const unsigned short* __restrict__ T1X, const unsigned short* __restrict__ T1H,
    const unsigned short* __restrict__ T2X, const unsigned short* __restrict__ T2H,
    const unsigned short* __restrict__ Wb, const float* __restrict__ C,
    const float* __restrict__ bias, const float* __restrict__ wc,
    float* __restrict__ out) {
  __shared__ float pre[32 * PSTR];  // 33792 B
  const int t = threadIdx.x;
  const int wv = t >> 6;         // gate
  const int l = t & 63;
  const int base = blockIdx.x * 32;
  const int lr = l & 15;
  const int lk = (l >> 4) * 8;

  f32x4 acc[2][4];
#pragma unroll
  for (int rb = 0; rb < 2; ++rb)
#pragma unroll
    for (int cf = 0; cf < 4; ++cf) acc[rb][cf] = (f32x4){0.f, 0.f, 0.f, 0.f};

  int r0 = base + lr, r1 = base + 16 + lr;
  int r0c = (r0 < NN) ? r0 : NN - 1;
  int r1c = (r1 < NN) ? r1 : NN - 1;

  const unsigned short* segp[6] = {Xb, T1X, T2X, Hb, T1H, T2H};
#pragma unroll
  for (int seg = 0; seg < 6; ++seg) {
    const unsigned short* sp = segp[seg];
#pragma unroll
    for (int h = 0; h < 2; ++h) {
      const int kc = seg * 2 + h;
      const int ko = h * 32 + lk;
      short8 a0 = *(const short8*)&sp[r0c * 64 + ko];
      short8 a1 = *(const short8*)&sp[r1c * 64 + ko];
#pragma unroll
      for (int cf = 0; cf < 4; ++cf) {
        short8 b = *(const short8*)&Wb[(wv * 64 + cf * 16 + lr) * 384 + kc * 32 + lk];
        acc[0][cf] = __builtin_amdgcn_mfma_f32_16x16x32_bf16(a0, b, acc[0][cf], 0, 0, 0);
        acc[1][cf] = __builtin_amdgcn_mfma_f32_16x16x32_bf16(a1, b, acc[1][cf], 0, 0, 0);
      }
    }
  }

  // exchange: pre[row][wv*64 + cf*16 + lr]
#pragma unroll
  for (int rb = 0; rb < 2; ++rb)
#pragma unroll
    for (int cf = 0; cf < 4; ++cf)
#pragma unroll
      for (int qq = 0; qq < 4; ++qq) {
        int row = rb * 16 + (l >> 4) * 4 + qq;
        pre[row * PSTR + wv * 64 + cf * 16 + lr] = acc[rb][cf][qq];
      }
  __syncthreads();

  // fused gate epilogue
  for (int i = t; i < 32 * 64; i += 256) {
    int m = i >> 6;
    int cc = i & 63;
    int n = base + m;
    if (n >= NN) continue;
    const float* pr = &pre[m * PSTR];
    float cv = C[n * 64 + cc];
    float pI = pr[cc]        + bias[cc]        + wc[cc] * cv;
    float pF = pr[64 + cc]   + bias[64 + cc]   + wc[64 + cc] * cv;
    float pT = pr[128 + cc]  + bias[128 + cc];
    float I = sigm(pI);
    float F = sigm(pF);
    float T = tanh_(pT);
    float Cn = F * cv + I * T;
    float pO = pr[192 + cc]  + bias[192 + cc]  + wc[128 + cc] * Cn;
    float O = sigm(pO);
    out[n * 64 + cc] = O * tanh_(Cn);
    out[NN * 64 + n * 64 + cc] = Cn;
  }
}

extern "C" void kernel_launch(void* const* d_in, const int* in_sizes, int n_in,
                              void* d_out, int out_size, void* d_ws, size_t ws_size,
                              hipStream_t stream) {
  const float* X  = (const float*)d_in[0];
  const int*   ei = (const int*)d_in[1];
  const float* ew = (const float*)d_in[2];
  const float* H  = (const float*)d_in[3];
  const float* C  = (const float*)d_in[4];
  const float* Wx = (const float*)d_in[5];
  const float* bx = (const float*)d_in[6];
  const float* Wh = (const float*)d_in[7];
  const float* bh = (const float*)d_in[8];
  const float* wc = (const float*)d_in[9];
  const float* bg = (const float*)d_in[10];
  float* out = (float*)d_out;
  float* ws = (float*)d_ws;

  const int* src = ei;
  const int* dst = ei + NE;
  float* deg = ws + OFF_DEG;     // becomes dinv
  int* cnt = (int*)(ws + OFF_CNT);
  int* rowptr = (int*)(ws + OFF_ROWPTR);
  int* bsum = (int*)(ws + OFF_BSUM);
  unsigned short* Wb = (unsigned short*)(ws + OFF_WB);
  float* bias = ws + OFF_BIAS;
  unsigned* elist = (unsigned*)(ws + OFF_ELIST);
  int* rank = (int*)(ws + OFF_RANK);
  unsigned short* Xb  = (unsigned short*)(ws + OFF_XB);
  unsigned short* Hb  = (unsigned short*)(ws + OFF_HB);
  unsigned short* T1X = (unsigned short*)(ws + OFF_T1X);
  unsigned short* T1H = (unsigned short*)(ws + OFF_T1H);
  unsigned short* T2X = (unsigned short*)(ws + OFF_T2X);
  unsigned short* T2H = (unsigned short*)(ws + OFF_T2H);

  const int NBLK = (NN + 1023) / 1024;  // 49

  k_zero<<<(100000 + 255) / 256, 256, 0, stream>>>((int*)ws, 100000);
  k_hc<<<HBLK + CBLK + WBLK, 256, 0, stream>>>(src, dst, ew, deg, cnt, rank,
                                               X, H, Xb, Hb,
                                               Wx, Wh, bx, bh, bg, Wb, bias);
  k_scanA<<<NBLK, 1024, 0, stream>>>(cnt, rowptr, bsum);
  k_scanB<<<1, 64, 0, stream>>>(bsum, rowptr, NBLK);
  k_scanC<<<NBLK, 1024, 0, stream>>>(rowptr, bsum, deg);
  k_scatter<<<(NE + 255) / 256, 256, 0, stream>>>(src, dst, ew, deg, rowptr, rank, elist);
  k_prop<<<NN / 4, 256, 0, stream>>>(rowptr, elist, Xb, Hb, T1X, T1H,
                                     nullptr, nullptr, 0);
  k_prop<<<NN / 4, 256, 0, stream>>>(rowptr, elist, T1X, T1H, T2X, T2H,
                                     Xb, Hb, 1);
  k_gates<<<(NN + 31) / 32, 256, 0, stream>>>(Xb, Hb, T1X, T1H, T2X, T2H,
                                              Wb, C, bias, wc, out);
}